// Round 15
// baseline (118.429 us; speedup 1.0000x reference)
//
#include <hip/hip_runtime.h>
#include <hip/hip_bf16.h>

#define M 8192
#define N 8192
#define K 512
#define BM 256
#define BN 256
#define BK 64
#define NT (K / BK)  // 8 K-tiles

typedef __attribute__((ext_vector_type(8))) short bf16x8;
typedef __attribute__((ext_vector_type(4))) float f32x4;
typedef __attribute__((ext_vector_type(8))) unsigned short us8;

__device__ inline void gload_lds16(const void* g, void* l) {
  __builtin_amdgcn_global_load_lds(
      (const __attribute__((address_space(1))) unsigned int*)g,
      (__attribute__((address_space(3))) unsigned int*)l, 16, 0, 0);
}

#define BARRIER()                          \
  do {                                     \
    asm volatile("" ::: "memory");         \
    __builtin_amdgcn_s_barrier();          \
    asm volatile("" ::: "memory");         \
  } while (0)

// Fused prep: cast f32 rows -> bf16, store INVERSE L2 norm (1/max(norm,1e-4)).
__global__ __launch_bounds__(256) void prep_kernel(const float* __restrict__ img,
                                                   const float* __restrict__ txt,
                                                   unsigned short* __restrict__ Abf,
                                                   unsigned short* __restrict__ Bbf,
                                                   float* __restrict__ w1,
                                                   float* __restrict__ w2) {
  const int half = blockIdx.x >> 11;
  const int lb = blockIdx.x & 2047;
  const float* in = half ? txt : img;
  unsigned short* outb = half ? Bbf : Abf;
  float* norms = half ? w2 : w1;

  const int gw = (lb * 256 + threadIdx.x) >> 6;
  const int lane = threadIdx.x & 63;
  const float4* rp4 = (const float4*)(in + (size_t)gw * K);
  float4 v0 = rp4[lane * 2];
  float4 v1 = rp4[lane * 2 + 1];
  float ss = v0.x * v0.x + v0.y * v0.y + v0.z * v0.z + v0.w * v0.w +
             v1.x * v1.x + v1.y * v1.y + v1.z * v1.z + v1.w * v1.w;
  float f[8] = {v0.x, v0.y, v0.z, v0.w, v1.x, v1.y, v1.z, v1.w};
  us8 o;
#pragma unroll
  for (int i = 0; i < 8; ++i) {
    __hip_bfloat16 b = __float2bfloat16(f[i]);
    o[i] = *(unsigned short*)&b;
  }
  *(us8*)(outb + (size_t)gw * K + lane * 8) = o;
#pragma unroll
  for (int off = 32; off > 0; off >>= 1) ss += __shfl_down(ss, off, 64);
  if (lane == 0) norms[gw] = 1.0f / fmaxf(sqrtf(ss), 1e-4f);
}

// 256x256 8-phase bf16 GEMM (r2's verified kernel) + two-level XCD swizzle
// (r3-proven FETCH fix) + inverse-norm multiply epilogue.
__global__ __launch_bounds__(512, 2) void gemm_kernel(const unsigned short* __restrict__ A,
                                                      const unsigned short* __restrict__ B,
                                                      const float* __restrict__ iw1,
                                                      const float* __restrict__ iw2,
                                                      float* __restrict__ C) {
  __shared__ __align__(128) unsigned short As[2][2][128 * 64];
  __shared__ __align__(128) unsigned short Bs[2][2][128 * 64];

  const int tid = threadIdx.x;
  const int wave = tid >> 6;
  const int lane = tid & 63;
  const int wr = wave >> 2;  // 0..1 : wave M-half
  const int wc = wave & 3;   // 0..3 : wave N-quarter (64 cols)
  const int fr = lane & 15;
  const int fq = lane >> 4;

  // Two-level XCD swizzle: xcd owns col-panels [xcd*4, xcd*4+4); idx walks
  // (row-panel, col-panel) row-major. Concurrent per-XCD working set:
  // 8 A-panels (2MB) + 4 B-panels (1MB) <= 4MB L2.
  const int xcd = blockIdx.x & 7;
  const int idx = blockIdx.x >> 3;              // 0..127
  const int bRow = (idx >> 2) * BM;             // 32 row-panels
  const int bCol = (xcd * 4 + (idx & 3)) * BN;  // 32 col-panels

  // Staging geometry: half-tile = 128 rows x 128 B, two 8 KB chunks.
  // Linear LDS dest; source col pre-swizzled (involution byte^=((row&7)<<4)).
  const int r0 = tid >> 3;        // chunk0 row, 0..63
  const int r1 = 64 + (tid >> 3); // chunk1 row
  const int csw = ((tid & 7) * 16) ^ ((r0 & 7) << 4);

  auto stageA = [&](int buf, int half, int kt) {
    gload_lds16(A + (size_t)(bRow + half * 128 + r0) * K + kt * BK + (csw >> 1),
                (char*)&As[buf][half][0] + wave * 1024);
    gload_lds16(A + (size_t)(bRow + half * 128 + r1) * K + kt * BK + (csw >> 1),
                (char*)&As[buf][half][0] + 8192 + wave * 1024);
  };
  auto stageB = [&](int buf, int half, int kt) {
    gload_lds16(B + (size_t)(bCol + half * 128 + r0) * K + kt * BK + (csw >> 1),
                (char*)&Bs[buf][half][0] + wave * 1024);
    gload_lds16(B + (size_t)(bCol + half * 128 + r1) * K + kt * BK + (csw >> 1),
                (char*)&Bs[buf][half][0] + 8192 + wave * 1024);
  };
  auto ldA = [&](int buf, int r, int cb) -> bf16x8 {
    return *(const bf16x8*)((const char*)&As[buf][wr][0] + r * 128 + (cb ^ ((r & 7) << 4)));
  };
  auto ldB = [&](int buf, int r, int cb) -> bf16x8 {
    return *(const bf16x8*)((const char*)&Bs[buf][wc >> 1][0] + r * 128 + (cb ^ ((r & 7) << 4)));
  };

  f32x4 acc[8][4] = {};
  bf16x8 a[4][2], bLo[2][2], bHi[2][2];
  const int bRowB = (wc & 1) * 64;  // wave's B row base within its half

  // Prologue: tile0 A+B, tile1 B (12 loads); first 8 must land.
  stageA(0, 0, 0);
  stageA(0, 1, 0);
  stageB(0, 0, 0);
  stageB(0, 1, 0);
  stageB(1, 0, 1);
  stageB(1, 1, 1);
  asm volatile("s_waitcnt vmcnt(4)" ::: "memory");
  BARRIER();

#define MFMA_Q(MB, BARR, NB)                                                      \
  _Pragma("unroll") for (int kk = 0; kk < 2; ++kk)                                \
      _Pragma("unroll") for (int m = 0; m < 4; ++m)                               \
          _Pragma("unroll") for (int n = 0; n < 2; ++n)                           \
              acc[(MB) + m][(NB) + n] = __builtin_amdgcn_mfma_f32_16x16x32_bf16(  \
                  a[m][kk], BARR[n][kk], acc[(MB) + m][(NB) + n], 0, 0, 0);

#pragma unroll
  for (int t = 0; t < NT; ++t) {
    const int cur = t & 1, nxt = cur ^ 1;

    // ---- phase 1: ds_read A m0-3 + B n0-1 ; stage A half0 (t+1)
#pragma unroll
    for (int m = 0; m < 4; ++m)
#pragma unroll
      for (int kk = 0; kk < 2; ++kk) a[m][kk] = ldA(cur, m * 16 + fr, kk * 64 + fq * 16);
#pragma unroll
    for (int n = 0; n < 2; ++n)
#pragma unroll
      for (int kk = 0; kk < 2; ++kk)
        bLo[n][kk] = ldB(cur, bRowB + n * 16 + fr, kk * 64 + fq * 16);
    if (t + 1 < NT) stageA(nxt, 0, t + 1);
    BARRIER();
    __builtin_amdgcn_s_setprio(1);
    MFMA_Q(0, bLo, 0)
    __builtin_amdgcn_s_setprio(0);
    BARRIER();

    // ---- phase 2: ds_read B n2-3 ; stage A half1 (t+1)
#pragma unroll
    for (int n = 0; n < 2; ++n)
#pragma unroll
      for (int kk = 0; kk < 2; ++kk)
        bHi[n][kk] = ldB(cur, bRowB + 32 + n * 16 + fr, kk * 64 + fq * 16);
    if (t + 1 < NT) stageA(nxt, 1, t + 1);
    BARRIER();
    __builtin_amdgcn_s_setprio(1);
    MFMA_Q(0, bHi, 2)
    __builtin_amdgcn_s_setprio(0);
    BARRIER();

    // ---- phase 3: ds_read A m4-7 ; stage B half0 (t+2)
#pragma unroll
    for (int m = 0; m < 4; ++m)
#pragma unroll
      for (int kk = 0; kk < 2; ++kk) a[m][kk] = ldA(cur, 64 + m * 16 + fr, kk * 64 + fq * 16);
    if (t + 2 < NT) stageB(cur, 0, t + 2);
    BARRIER();
    __builtin_amdgcn_s_setprio(1);
    MFMA_Q(4, bLo, 0)
    __builtin_amdgcn_s_setprio(0);
    BARRIER();

    // ---- phase 4: stage B half1 (t+2) ; MFMA ; counted vmcnt ; barrier
    if (t + 2 < NT) stageB(cur, 1, t + 2);
    BARRIER();
    __builtin_amdgcn_s_setprio(1);
    MFMA_Q(4, bHi, 2)
    __builtin_amdgcn_s_setprio(0);
    if (t < NT - 2) {
      asm volatile("s_waitcnt vmcnt(4)" ::: "memory");
    } else if (t == NT - 2) {
      asm volatile("s_waitcnt vmcnt(0)" ::: "memory");
    }
    BARRIER();
  }
#undef MFMA_Q

  // Epilogue: C/D layout col = lane&15, row = (lane>>4)*4 + reg;
  // multiply by inverse norms (no div).
#pragma unroll
  for (int m = 0; m < 8; ++m) {
    const int row0 = bRow + wr * 128 + m * 16 + fq * 4;
    float i1v[4];
#pragma unroll
    for (int r = 0; r < 4; ++r) i1v[r] = iw1[row0 + r];
#pragma unroll
    for (int n = 0; n < 4; ++n) {
      const int col = bCol + wc * 64 + n * 16 + fr;
      const float i2v = iw2[col];
      f32x4 v = acc[m][n];
#pragma unroll
      for (int r = 0; r < 4; ++r)
        C[(size_t)(row0 + r) * N + col] = v[r] * i1v[r] * i2v;
    }
  }
}

extern "C" void kernel_launch(void* const* d_in, const int* in_sizes, int n_in,
                              void* d_out, int out_size, void* d_ws, size_t ws_size,
                              hipStream_t stream) {
  (void)in_sizes; (void)n_in; (void)out_size; (void)ws_size;
  const float* img = (const float*)d_in[0];
  const float* txt = (const float*)d_in[1];
  float* out = (float*)d_out;

  unsigned short* Abf = (unsigned short*)d_ws;
  unsigned short* Bbf = Abf + (size_t)M * K;
  float* w1 = (float*)(Bbf + (size_t)N * K);
  float* w2 = w1 + M;

  prep_kernel<<<4096, 256, 0, stream>>>(img, txt, Abf, Bbf, w1, w2);
  gemm_kernel<<<(M / BM) * (N / BN), 512, 0, stream>>>(Abf, Bbf, w1, w2, out);
}